// Round 9
// baseline (257.228 us; speedup 1.0000x reference)
//
#include <hip/hip_runtime.h>
#include <math.h>

// ---------------- fast transcendental helpers ----------------
#if __has_builtin(__builtin_amdgcn_exp2f)
#define EXP2F(x) __builtin_amdgcn_exp2f(x)
#else
#define EXP2F(x) exp2f(x)
#endif
#if __has_builtin(__builtin_amdgcn_logf)
#define LOG2F(x) __builtin_amdgcn_logf(x)
#else
#define LOG2F(x) log2f(x)
#endif
#if __has_builtin(__builtin_amdgcn_rcpf)
#define RCPF(x) __builtin_amdgcn_rcpf(x)
#else
#define RCPF(x) (1.0f / (x))
#endif

#define LOG2E 1.4426950408889634f

// Counted vmem waits (T4): wait until at most N of this wave's VMEM ops
// remain outstanding. vmcnt is FIFO -> drains the OLDEST first.
#define WAITVM0() asm volatile("s_waitcnt vmcnt(0)" ::: "memory")
#define WAITVM4() asm volatile("s_waitcnt vmcnt(4)" ::: "memory")
#define WAITVM8() asm volatile("s_waitcnt vmcnt(8)" ::: "memory")

typedef __bf16 bf16x8 __attribute__((ext_vector_type(8)));
typedef float f32x4 __attribute__((ext_vector_type(4)));

__device__ __forceinline__ float silu_f(float v) {
    return v * RCPF(1.0f + EXP2F(-v * LOG2E));
}
__device__ __forceinline__ float softplus_f(float v) {
    return fmaxf(v, 0.0f) + log1pf(__expf(-fabsf(v)));
}

// quad_perm DPP add. 0xB1 = swap pairs -> pair sum.
template <int CTRL>
__device__ __forceinline__ float dpp_add(float v) {
    int r = __builtin_amdgcn_update_dpp(0, __float_as_int(v), CTRL, 0xF, 0xF, true);
    return v + __int_as_float(r);
}

// bf16 round-to-nearest-even helpers
__device__ __forceinline__ unsigned short bf16_rne(float f) {
    unsigned int u = __float_as_uint(f);
    return (unsigned short)((u + 0x7FFFu + ((u >> 16) & 1u)) >> 16);
}
__device__ __forceinline__ unsigned short bf16_hi(float f, float& rem) {
    unsigned int u = __float_as_uint(f);
    unsigned int hb = (u + 0x7FFFu + ((u >> 16) & 1u)) >> 16;
    rem = f - __uint_as_float(hb << 16);
    return (unsigned short)hb;
}

// async global->LDS 16B (wave-uniform LDS base + lane*16)
__device__ __forceinline__ void async_g2l16(const void* g, void* l) {
    __builtin_amdgcn_global_load_lds(
        (const __attribute__((address_space(1))) unsigned int*)g,
        (__attribute__((address_space(3))) unsigned int*)l, 16, 0, 0);
}

// ---------------- merged conversion kernel (v8-verbatim) ----------------
__global__ __launch_bounds__(256) void conv_all_k(
    const float* __restrict__ x,
    unsigned short* __restrict__ xh,
    const float* __restrict__ w_in,
    unsigned short* __restrict__ wih, unsigned short* __restrict__ wil,
    const float* __restrict__ w_out,
    unsigned short* __restrict__ woh, unsigned short* __restrict__ wol,
    const float* __restrict__ w_xp,
    const float* __restrict__ w_dt,
    const float* __restrict__ b_dt,
    unsigned short* __restrict__ wbh, unsigned short* __restrict__ wbl,
    float* __restrict__ bias_full)
{
    __shared__ float shmem[6272];
    const int bid = blockIdx.x;
    const int t = threadIdx.x;
    if (bid < 768) {
#pragma unroll
        for (int r = 0; r < 4; ++r) {
            int i = (bid + 768 * r) * 256 + t;
            float4 v = ((const float4*)x)[i];
            ushort4 h;
            h.x = bf16_rne(v.x);
            h.y = bf16_rne(v.y);
            h.z = bf16_rne(v.z);
            h.w = bf16_rne(v.w);
            ((ushort4*)xh)[i] = h;
        }
        return;
    }
    if (bid < 2496) {
        const float* W;
        unsigned short *Th, *Tl;
        int N, bx, by;
        if (bid < 1920) {
            int b2 = bid - 768;
            W = w_in; Th = wih; Tl = wil; N = 1536;
            bx = b2 % 48; by = b2 / 48;
        } else {
            int b3 = bid - 1920;
            W = w_out; Th = woh; Tl = wol; N = 768;
            bx = b3 % 24; by = b3 / 24;
        }
        const int K = 768;
        float (*tile)[33] = (float (*)[33])shmem;
        const int tx = t & 31, ty = t >> 5;
        const int n0 = bx * 32, k0 = by * 32;
#pragma unroll
        for (int r = 0; r < 4; ++r)
            tile[ty + r * 8][tx] = W[(size_t)(k0 + ty + r * 8) * N + n0 + tx];
        __syncthreads();
#pragma unroll
        for (int r = 0; r < 4; ++r) {
            float v = tile[tx][ty + r * 8];
            float rem;
            unsigned short h = bf16_hi(v, rem);
            size_t o = (size_t)(n0 + ty + r * 8) * K + k0 + tx;
            Th[o] = h;
            Tl[o] = bf16_rne(rem);
        }
        return;
    }
    if (bid < 2640) {
        // W_dt_eff 64x64 tile
        int b4 = bid - 2496;
        int bxw = b4 % 12, byw = b4 / 12;
        const int kd0 = byw * 64, dd0 = bxw * 64;
        float* As = shmem;              // [64][49]
        float* Ws = shmem + 64 * 49;    // [48][65]
        {
            int r = t >> 2;
            int c4 = (t & 3) * 4;
#pragma unroll
            for (int s = 0; s < 3; ++s) {
                float4 a = *(const float4*)&w_xp[(size_t)(kd0 + r) * 112 + c4 + 16 * s];
                As[r * 49 + c4 + 16 * s + 0] = a.x;
                As[r * 49 + c4 + 16 * s + 1] = a.y;
                As[r * 49 + c4 + 16 * s + 2] = a.z;
                As[r * 49 + c4 + 16 * s + 3] = a.w;
            }
            int rw = t >> 4;
            int cw = (t & 15) * 4;
#pragma unroll
            for (int s = 0; s < 3; ++s) {
                float4 w = *(const float4*)&w_dt[(size_t)(rw + 16 * s) * 768 + dd0 + cw];
                Ws[(rw + 16 * s) * 65 + cw + 0] = w.x;
                Ws[(rw + 16 * s) * 65 + cw + 1] = w.y;
                Ws[(rw + 16 * s) * 65 + cw + 2] = w.z;
                Ws[(rw + 16 * s) * 65 + cw + 3] = w.w;
            }
        }
        __syncthreads();
        const int ty = t >> 4, tx = t & 15;
        float acc[4][4];
#pragma unroll
        for (int i = 0; i < 4; ++i)
#pragma unroll
            for (int j = 0; j < 4; ++j) acc[i][j] = 0.0f;
        for (int k = 0; k < 48; ++k) {
            float ar[4], wr[4];
#pragma unroll
            for (int i = 0; i < 4; ++i) ar[i] = As[(ty * 4 + i) * 49 + k];
#pragma unroll
            for (int j = 0; j < 4; ++j) wr[j] = Ws[k * 65 + tx * 4 + j];
#pragma unroll
            for (int i = 0; i < 4; ++i)
#pragma unroll
                for (int j = 0; j < 4; ++j)
                    acc[i][j] = fmaf(ar[i], wr[j], acc[i][j]);
        }
        __syncthreads();
        float* Ot = shmem;              // [64][65]
#pragma unroll
        for (int i = 0; i < 4; ++i)
#pragma unroll
            for (int j = 0; j < 4; ++j)
                Ot[(tx * 4 + j) * 65 + ty * 4 + i] = acc[i][j];
        __syncthreads();
        int dl = t >> 2, c0 = (t & 3) * 16;
#pragma unroll
        for (int k = 0; k < 16; ++k) {
            float v = Ot[dl * 65 + c0 + k];
            float rem;
            unsigned short h = bf16_hi(v, rem);
            size_t o = (size_t)(64 + dd0 + dl) * 768 + kd0 + c0 + k;
            wbh[o] = h;
            wbl[o] = bf16_rne(rem);
        }
        return;
    }
    if (bid < 2688) {
        int b5 = bid - 2640;
        int bxb = b5 & 1, byb = b5 >> 1;
        const int n0 = bxb * 32, k0 = byb * 32;
        float (*tile)[33] = (float (*)[33])shmem;
        const int tx = t & 31, ty = t >> 5;
#pragma unroll
        for (int r = 0; r < 4; ++r)
            tile[ty + r * 8][tx] = w_xp[(size_t)(k0 + ty + r * 8) * 112 + 48 + n0 + tx];
        __syncthreads();
#pragma unroll
        for (int r = 0; r < 4; ++r) {
            float v = tile[tx][ty + r * 8];
            float rem;
            unsigned short h = bf16_hi(v, rem);
            size_t o = (size_t)(n0 + ty + r * 8) * 768 + k0 + tx;
            wbh[o] = h;
            wbl[o] = bf16_rne(rem);
        }
        return;
    }
#pragma unroll
    for (int i = 0; i < 4; ++i) {
        int idx = t + 256 * i;
        if (idx < 896)
            bias_full[idx] = (idx >= 64 && idx < 832) ? b_dt[idx - 64] : 0.0f;
    }
}

// ---------------- 2-term split-bf16 MFMA GEMM, 128x64 tile ----------------
// v10: 3-deep pipeline with counted vmcnt (T4). Per iter t:
//   waitvm(4)   -- drains only tile t (issued 2 iters ago; ~free by now);
//                  tiles t+1,t+2 stay in flight across the barrier
//   barrier     -- all waves' tile-t DMAs have landed
//   stage(t+2)  -- writes tile (t-1)'s slot; its readers finished before
//                  this barrier (WAR-safe)
//   ds_read/MFMA on buf[t%3]
// Last iteration uses waitvm(0) (no newer tile -> counted wait is vacuous).
template <int EPI, int WRX>
__global__ __launch_bounds__(256, 3) void mgemm_k(
    const unsigned short* __restrict__ Ah,
    const unsigned short* __restrict__ Bth, const unsigned short* __restrict__ Btl,
    const float* __restrict__ bias,
    float* __restrict__ C, int K, int ldc, int nby,
    unsigned short* __restrict__ xh, unsigned short* __restrict__ xl)
{
    __shared__ unsigned short smem[3][8192];  // 3 buf x (Ah 128x32 | Bh 64x32 | Bl 64x32)

    const int t = threadIdx.x;
    const int wave = t >> 6, lane = t & 63;
    const int bx = blockIdx.x / nby, by = blockIdx.x % nby;
    const int bm = by * 128, bn = bx * 64;
    const int mw = (wave >> 1) * 64, nw = (wave & 1) * 32;

    // staging: wave0 Ah[0:64], wave1 Ah[64:128], wave2 Bh[0:64], wave3 Bl[0:64]
    // each wave: 4 global_load_lds per tile
    const unsigned short* smat;
    int row0, lmoff;
    if      (wave == 0) { smat = Ah;  row0 = bm;      lmoff = 0; }
    else if (wave == 1) { smat = Ah;  row0 = bm + 64; lmoff = 4096; }
    else if (wave == 2) { smat = Bth; row0 = bn;      lmoff = 8192; }
    else                { smat = Btl; row0 = bn;      lmoff = 12288; }
    const int lr = lane >> 2;
    const int kq = (lane & 3) ^ ((lane >> 3) & 3);
    const unsigned short* gbase = smat + (size_t)(row0 + lr) * K + kq * 8;

    const int la = lane & 15, g4 = lane >> 4;
    const int fo = (g4 ^ ((la >> 1) & 3)) * 8;
    const int aoff = (mw + la) * 32 + fo;
    const int boff = (nw + la) * 32 + fo;

    f32x4 acc[4][2];
#pragma unroll
    for (int i = 0; i < 4; ++i)
#pragma unroll
        for (int j = 0; j < 2; ++j) acc[i][j] = (f32x4){0.f, 0.f, 0.f, 0.f};

    auto stage = [&](int buf, int k0) {
        char* lm = (char*)&smem[buf][0] + lmoff;
        const unsigned short* g = gbase + k0;
#pragma unroll
        for (int j = 0; j < 4; ++j)
            async_g2l16(g + (size_t)j * 16 * K, lm + j * 1024);
    };

    stage(0, 0);
    if (32 < K) stage(1, 32);

    int cur = 0, stg = 2;
    for (int k0 = 0; k0 < K; k0 += 32) {
        if (k0 + 32 < K) { WAITVM4(); } else { WAITVM0(); }
        __syncthreads();
        if (k0 + 64 < K) {
            stage(stg, k0 + 64);
            stg = (stg == 2) ? 0 : stg + 1;
        }

        const unsigned short* base = &smem[cur][0];
        const unsigned short* pAh = base + aoff;
        const unsigned short* pBh = base + 4096 + boff;
        const unsigned short* pBl = base + 6144 + boff;

        bf16x8 fah[4], fbh[2], fbl[2];
#pragma unroll
        for (int i = 0; i < 4; ++i)
            fah[i] = *(const bf16x8*)(pAh + i * 512);
#pragma unroll
        for (int j = 0; j < 2; ++j) {
            fbh[j] = *(const bf16x8*)(pBh + j * 512);
            fbl[j] = *(const bf16x8*)(pBl + j * 512);
        }
#pragma unroll
        for (int i = 0; i < 4; ++i)
#pragma unroll
            for (int j = 0; j < 2; ++j)
                acc[i][j] = __builtin_amdgcn_mfma_f32_16x16x32_bf16(fah[i], fbh[j], acc[i][j], 0, 0, 0);
#pragma unroll
        for (int i = 0; i < 4; ++i)
#pragma unroll
            for (int j = 0; j < 2; ++j)
                acc[i][j] = __builtin_amdgcn_mfma_f32_16x16x32_bf16(fah[i], fbl[j], acc[i][j], 0, 0, 0);
        cur = (cur == 2) ? 0 : cur + 1;
    }
    // final barrier before epilogue not needed: acc is register-resident and
    // each wave's last ds_reads completed before its MFMAs consumed them.

#pragma unroll
    for (int i = 0; i < 4; ++i) {
        int row = bm + mw + i * 16 + g4 * 4;
#pragma unroll
        for (int j = 0; j < 2; ++j) {
            int col = bn + nw + j * 16 + la;
            float bz = bias ? bias[col] : 0.0f;
#pragma unroll
            for (int r = 0; r < 4; ++r) {
                float v = acc[i][j][r] + bz;
                if (EPI == 1) v = silu_f(v);
                C[(size_t)(row + r) * ldc + col] = v;
                if (WRX) {
                    if (col < 768) {
                        float rem;
                        unsigned short hh = bf16_hi(v, rem);
                        xh[(size_t)(row + r) * 768 + col] = hh;
                        xl[(size_t)(row + r) * 768 + col] = bf16_rne(rem);
                    }
                }
            }
        }
    }
}

// ---------------- 3-term split-bf16 MFMA GEMM, 128x64 tile, 3-deep --------
__global__ __launch_bounds__(256, 2) void mgemm3_k(
    const unsigned short* __restrict__ Ahp, const unsigned short* __restrict__ Alp,
    const unsigned short* __restrict__ Bth, const unsigned short* __restrict__ Btl,
    const float* __restrict__ bias,
    float* __restrict__ C, int K, int ldc, int nby)
{
    __shared__ unsigned short smem[3][12288];  // 3 buf x (Ah | Al | Bh | Bl)

    const int t = threadIdx.x;
    const int wave = t >> 6, lane = t & 63;
    const int bx = blockIdx.x / nby, by = blockIdx.x % nby;
    const int bm = by * 128, bn = bx * 64;
    const int mw = (wave >> 1) * 64, nw = (wave & 1) * 32;

    // staging: wave0 Ah (8 inst), wave1 Al (8), wave2 Bh (4), wave3 Bl (4)
    const unsigned short* smat;
    int row0, ninst, lmoff;
    if      (wave == 0) { smat = Ahp; row0 = bm; ninst = 8; lmoff = 0; }
    else if (wave == 1) { smat = Alp; row0 = bm; ninst = 8; lmoff = 8192; }
    else if (wave == 2) { smat = Bth; row0 = bn; ninst = 4; lmoff = 16384; }
    else                { smat = Btl; row0 = bn; ninst = 4; lmoff = 20480; }
    const int lr = lane >> 2;
    const int kq = (lane & 3) ^ ((lane >> 3) & 3);
    const unsigned short* gbase = smat + (size_t)(row0 + lr) * K + kq * 8;

    const int la = lane & 15, g4 = lane >> 4;
    const int fo = (g4 ^ ((la >> 1) & 3)) * 8;
    const int aoff = (mw + la) * 32 + fo;
    const int boff = (nw + la) * 32 + fo;

    f32x4 acc[4][2];
#pragma unroll
    for (int i = 0; i < 4; ++i)
#pragma unroll
        for (int j = 0; j < 2; ++j) acc[i][j] = (f32x4){0.f, 0.f, 0.f, 0.f};

    auto stage = [&](int buf, int k0) {
        char* lm = (char*)&smem[buf][0] + lmoff;
        const unsigned short* g = gbase + k0;
        if (ninst == 8) {
#pragma unroll
            for (int j = 0; j < 8; ++j)
                async_g2l16(g + (size_t)j * 16 * K, lm + j * 1024);
        } else {
#pragma unroll
            for (int j = 0; j < 4; ++j)
                async_g2l16(g + (size_t)j * 16 * K, lm + j * 1024);
        }
    };

    stage(0, 0);
    if (32 < K) stage(1, 32);

    int cur = 0, stg = 2;
    for (int k0 = 0; k0 < K; k0 += 32) {
        if (k0 + 32 < K) {
            if (ninst == 8) { WAITVM8(); } else { WAITVM4(); }
        } else {
            WAITVM0();
        }
        __syncthreads();
        if (k0 + 64 < K) {
            stage(stg, k0 + 64);
            stg = (stg == 2) ? 0 : stg + 1;
        }

        const unsigned short* base = &smem[cur][0];
        const unsigned short* pAh = base + aoff;
        const unsigned short* pAl = base + 4096 + aoff;
        const unsigned short* pBh = base + 8192 + boff;
        const unsigned short* pBl = base + 10240 + boff;

        bf16x8 fah[4], fal[4], fbh[2], fbl[2];
#pragma unroll
        for (int i = 0; i < 4; ++i) {
            fah[i] = *(const bf16x8*)(pAh + i * 512);
            fal[i] = *(const bf16x8*)(pAl + i * 512);
        }
#pragma unroll
        for (int j = 0; j < 2; ++j) {
            fbh[j] = *(const bf16x8*)(pBh + j * 512);
            fbl[j] = *(const bf16x8*)(pBl + j * 512);
        }
#pragma unroll
        for (int i = 0; i < 4; ++i)
#pragma unroll
            for (int j = 0; j < 2; ++j)
                acc[i][j] = __builtin_amdgcn_mfma_f32_16x16x32_bf16(fah[i], fbh[j], acc[i][j], 0, 0, 0);
#pragma unroll
        for (int i = 0; i < 4; ++i)
#pragma unroll
            for (int j = 0; j < 2; ++j)
                acc[i][j] = __builtin_amdgcn_mfma_f32_16x16x32_bf16(fah[i], fbl[j], acc[i][j], 0, 0, 0);
#pragma unroll
        for (int i = 0; i < 4; ++i)
#pragma unroll
            for (int j = 0; j < 2; ++j)
                acc[i][j] = __builtin_amdgcn_mfma_f32_16x16x32_bf16(fal[i], fbh[j], acc[i][j], 0, 0, 0);
        cur = (cur == 2) ? 0 : cur + 1;
    }

#pragma unroll
    for (int i = 0; i < 4; ++i) {
        int row = bm + mw + i * 16 + g4 * 4;
#pragma unroll
        for (int j = 0; j < 2; ++j) {
            int col = bn + nw + j * 16 + la;
            float bz = bias[col];
#pragma unroll
            for (int r = 0; r < 4; ++r) {
                float v = acc[i][j][r] + bz;
                if (col >= 64) v = softplus_f(v);
                C[(size_t)(row + r) * ldc + col] = v;
            }
        }
    }
}

// ---------------- sequential fractal scan (v8-verbatim, 97.2µs) -----------
#define L_LEN 1024
#define CH 32
#define NCH (L_LEN / CH)
#define CHP (CH + 4)

__global__ __launch_bounds__(512) void scan_k(
    const float* __restrict__ xz,    // M x 1536 (silu applied to both halves)
    const float* __restrict__ bcdt,  // M x 896 (BC | dt)
    const float* __restrict__ A_log,
    unsigned short* __restrict__ ybh)  // M x 768 bf16 of y*silu(z)
{
    __shared__ float xdt_t[2][16][CHP];
    __shared__ float ds_t[2][16][CHP];
    __shared__ float B0s[2][16][CHP];
    __shared__ float B1s[2][16][CHP];
    __shared__ float C0s[2][16][CHP];
    __shared__ float C1s[2][16][CHP];
    __shared__ float ysp[2][CH][16][8];

    const int t  = threadIdx.x;
    const int b  = blockIdx.y;
    const int d0 = blockIdx.x * 16;
    const size_t rowbase = (size_t)b * L_LEN;
    const bool is_chain = (t < 256);

    const int n  = t & 15;
    const int dl = (t >> 4) & 15;
    const int np = n >> 1;
    float negAl2e = 0.0f, h0 = 0.0f, h1 = 0.0f;
    float s2 = 1.0f, lT = 0.0f;
    if (is_chain) {
        negAl2e = -__expf(A_log[n]) * LOG2E;
        float phase = 6.283185307179586f * (float)n / 16.0f;
        h0 = 0.01f * cosf(phase);
        h1 = 0.01f * sinf(phase);
        lT = LOG2F(fmaf(h0, h0, fmaf(h1, h1, 1e-8f)));   // s2=1 -> lT = lq0
    }

    const int t2 = t - 256;
    const int hl = t2 >> 2;
    const int hf = (t2 & 3) * 4;

    auto stage = [&](int cc) {
        const int bi = cc & 1;
        if (t2 < 128) {
            size_t row = rowbase + cc * CH + hl;
            float4 rx = *(const float4*)&xz[row * 1536 + d0 + hf];
            float4 rd = *(const float4*)&bcdt[row * 896 + 64 + d0 + hf];
            xdt_t[bi][hf + 0][hl] = rx.x * rd.x;
            xdt_t[bi][hf + 1][hl] = rx.y * rd.y;
            xdt_t[bi][hf + 2][hl] = rx.z * rd.z;
            xdt_t[bi][hf + 3][hl] = rx.w * rd.w;
            ds_t[bi][hf + 0][hl] = rd.x;
            ds_t[bi][hf + 1][hl] = rd.y;
            ds_t[bi][hf + 2][hl] = rd.z;
            ds_t[bi][hf + 3][hl] = rd.w;
        }
#pragma unroll
        for (int i = 0; i < 2; ++i) {
            int idx = t2 + 256 * i;
            int lb = idx >> 4, j4 = (idx & 15) * 4;
            float4 rbc = *(const float4*)&bcdt[(rowbase + cc * CH + lb) * 896 + j4];
            if (j4 < 32) {
                int nn = j4 >> 1;
                B0s[bi][nn][lb]     = rbc.x;
                B1s[bi][nn][lb]     = rbc.y;
                B0s[bi][nn + 1][lb] = rbc.z;
                B1s[bi][nn + 1][lb] = rbc.w;
            } else {
                int nn = (j4 - 32) >> 1;
                C0s[bi][nn][lb]     = rbc.x;
                C1s[bi][nn][lb]     = rbc.y;
                C0s[bi][nn + 1][lb] = rbc.z;
                C1s[bi][nn + 1][lb] = rbc.w;
            }
        }
    };

    auto store_y = [&](int cs) {
        if (t2 >= 128) return;
        const int bi = cs & 1;
        size_t row = rowbase + cs * CH + hl;
        float4 zq = *(const float4*)&xz[row * 1536 + 768 + d0 + hf];
        float yr[4];
#pragma unroll
        for (int j = 0; j < 4; ++j) {
            float4 p0 = *(const float4*)&ysp[bi][hl][hf + j][0];
            float4 p1 = *(const float4*)&ysp[bi][hl][hf + j][4];
            yr[j] = ((p0.x + p0.y) + (p0.z + p0.w)) + ((p1.x + p1.y) + (p1.z + p1.w));
        }
        ushort4 hh;
        hh.x = bf16_rne(yr[0] * zq.x);
        hh.y = bf16_rne(yr[1] * zq.y);
        hh.z = bf16_rne(yr[2] * zq.z);
        hh.w = bf16_rne(yr[3] * zq.w);
        *(ushort4*)&ybh[row * 768 + d0 + hf] = hh;
    };

    if (!is_chain) stage(0);
    __syncthreads();

    for (int c = 0; c < NCH; ++c) {
        if (is_chain) {
            __builtin_amdgcn_s_setprio(1);
            const int bi = c & 1;
            const float* xr  = &xdt_t[bi][dl][0];
            const float* dr  = &ds_t[bi][dl][0];
            const float* b0r = &B0s[bi][n][0];
            const float* b1r = &B1s[bi][n][0];
            const float* c0r = &C0s[bi][n][0];
            const float* c1r = &C1s[bi][n][0];

            float4 px  = *(const float4*)(xr);
            float4 pd  = *(const float4*)(dr);
            float4 pb0 = *(const float4*)(b0r);
            float4 pb1 = *(const float4*)(b1r);
            float4 pc0 = *(const float4*)(c0r);
            float4 pc1 = *(const float4*)(c1r);

            for (int l4 = 0; l4 < CH; l4 += 4) {
                float4 cx = px, cd = pd, cb0 = pb0, cb1 = pb1, cc0 = pc0, cc1 = pc1;
                if (l4 + 4 < CH) {
                    px  = *(const float4*)(xr  + l4 + 4);
                    pd  = *(const float4*)(dr  + l4 + 4);
                    pb0 = *(const float4*)(b0r + l4 + 4);
                    pb1 = *(const float4*)(b1r + l4 + 4);
                    pc0 = *(const float4*)(c0r + l4 + 4);
                    pc1 = *(const float4*)(c1r + l4 + 4);
                }
                const float xv[4]  = {cx.x,  cx.y,  cx.z,  cx.w};
                const float dv[4]  = {cd.x,  cd.y,  cd.z,  cd.w};
                const float C0v[4] = {cc0.x, cc0.y, cc0.z, cc0.w};
                const float C1v[4] = {cc1.x, cc1.y, cc1.z, cc1.w};

                // off-path hoists: coefficient and B*x*dt for the 4 steps
                float cfv[4], bx0[4], bx1[4];
                const float B0v[4] = {cb0.x, cb0.y, cb0.z, cb0.w};
                const float B1v[4] = {cb1.x, cb1.y, cb1.z, cb1.w};
#pragma unroll
                for (int u = 0; u < 4; ++u) {
                    cfv[u] = fmaf(EXP2F(dv[u] * negAl2e), -0.25f, 0.25f);
                    bx0[u] = B0v[u] * xv[u];
                    bx1[u] = B1v[u] * xv[u];
                }

#pragma unroll
                for (int u = 0; u < 4; ++u) {
                    float g = s2 * EXP2F(cfv[u] * lT);
                    h0 = fmaf(h0, g, bx0[u]);
                    h1 = fmaf(h1, g, bx1[u]);
                    float q  = fmaf(h0, h0, fmaf(h1, h1, 1e-8f));
                    float q2 = q * q;                       // Estrin [3/3] Pade
                    float num = fmaf(q2, q + 378.0f,              fmaf(17325.0f, q, 135135.0f));
                    float den = fmaf(q2, fmaf(28.0f, q, 3150.0f), fmaf(62370.0f, q, 135135.0f));
                    s2 = num * RCPF(den);
                    lT = LOG2F(s2 * s2 * q);                // log2(tanh^2 m)

                    float yv = s2 * fmaf(C0v[u], h0, C1v[u] * h1);
                    yv = dpp_add<0xB1>(yv);                 // pair sum
                    if ((n & 1) == 0) ysp[bi][l4 + u][dl][np] = yv;
                }
            }
            __builtin_amdgcn_s_setprio(0);
        } else {
            if (c + 1 < NCH) stage(c + 1);
            if (c >= 1) store_y(c - 1);
        }
        __syncthreads();
    }
    if (!is_chain) store_y(NCH - 1);
}

// ---------------- launcher ----------------
extern "C" void kernel_launch(void* const* d_in, const int* in_sizes, int n_in,
                              void* d_out, int out_size, void* d_ws, size_t ws_size,
                              hipStream_t stream)
{
    const float* x     = (const float*)d_in[0];
    const float* w_in  = (const float*)d_in[1];
    const float* w_xp  = (const float*)d_in[2];
    const float* w_dt  = (const float*)d_in[3];
    const float* b_dt  = (const float*)d_in[4];
    const float* w_out = (const float*)d_in[5];
    const float* b_out = (const float*)d_in[6];
    const float* A_log = (const float*)d_in[7];
    float* out = (float*)d_out;

    const int M = 4096;
    float* xz        = (float*)d_ws;                       // M*1536 f32
    float* bcdt      = xz + (size_t)M * 1536;              // M*896  f32
    float* bias_full = bcdt + (size_t)M * 896;             // 896    f32
    unsigned short* ah   = (unsigned short*)(bias_full + 896);  // M*768
    unsigned short* ybh  = ah   + (size_t)M * 768;         // M*768
    unsigned short* xinh = ybh  + (size_t)M * 768;         // M*768
    unsigned short* xinl = xinh + (size_t)M * 768;         // M*768
    unsigned short* wh   = xinl + (size_t)M * 768;         // 1536*768
    unsigned short* wl   = wh   + (size_t)1536 * 768;
    unsigned short* voh  = wl   + (size_t)1536 * 768;      // 768*768
    unsigned short* vol  = voh  + (size_t)768 * 768;
    unsigned short* wbh  = vol  + (size_t)768 * 768;       // 896*768
    unsigned short* wbl  = wbh  + (size_t)896 * 768;

    dim3 blk(256);

    // 1) conversions: x bf16, weight transposes/splits, W_dt_eff, bias
    conv_all_k<<<dim3(2689), blk, 0, stream>>>(
        x, ah, w_in, wh, wl, w_out, voh, vol,
        w_xp, w_dt, b_dt, wbh, wbl, bias_full);

    // 2) xz = silu(x @ in_proj_w); also emits x_in bf16 h/l (cols<768)
    mgemm_k<1, 1><<<dim3(24 * 32), blk, 0, stream>>>(
        ah, wh, wl, (const float*)nullptr, xz, 768, 1536, 32, xinh, xinl);

    // 3) bcdt = [x_in @ w_xp[:,48:] | softplus(x_in @ W_dt_eff + b_dt)]
    mgemm3_k<<<dim3(14 * 32), blk, 0, stream>>>(
        xinh, xinl, wbh, wbl, bias_full, bcdt, 768, 896, 32);

    // 4) scan -> ybh = bf16(y_scan * silu(z))
    scan_k<<<dim3(48, 4), dim3(512), 0, stream>>>(xz, bcdt, A_log, ybh);

    // 5) out = yb @ out_proj_w + b_out
    mgemm_k<0, 0><<<dim3(12 * 32), blk, 0, stream>>>(
        ybh, voh, vol, b_out, out, 768, 768, 32,
        (unsigned short*)nullptr, (unsigned short*)nullptr);
}

// Round 10
// 256.629 us; speedup vs baseline: 1.0023x; 1.0023x over previous
//
#include <hip/hip_runtime.h>
#include <math.h>

// ---------------- fast transcendental helpers ----------------
#if __has_builtin(__builtin_amdgcn_exp2f)
#define EXP2F(x) __builtin_amdgcn_exp2f(x)
#else
#define EXP2F(x) exp2f(x)
#endif
#if __has_builtin(__builtin_amdgcn_logf)
#define LOG2F(x) __builtin_amdgcn_logf(x)
#else
#define LOG2F(x) log2f(x)
#endif
#if __has_builtin(__builtin_amdgcn_rcpf)
#define RCPF(x) __builtin_amdgcn_rcpf(x)
#else
#define RCPF(x) (1.0f / (x))
#endif

#define LOG2E 1.4426950408889634f

// Drain this wave's global_load_lds DMAs. REQUIRED before the barrier that
// publishes a freshly staged LDS buffer (v7 post-timing race: compiler does
// not conservatively drain vmcnt at __syncthreads in the dbuf shape).
#define DRAIN_VMEM() asm volatile("s_waitcnt vmcnt(0)" ::: "memory")

typedef __bf16 bf16x8 __attribute__((ext_vector_type(8)));
typedef float f32x4 __attribute__((ext_vector_type(4)));

__device__ __forceinline__ float silu_f(float v) {
    return v * RCPF(1.0f + EXP2F(-v * LOG2E));
}
__device__ __forceinline__ float softplus_f(float v) {
    return fmaxf(v, 0.0f) + log1pf(__expf(-fabsf(v)));
}

// quad_perm DPP add. 0xB1 = swap pairs -> pair sum.
template <int CTRL>
__device__ __forceinline__ float dpp_add(float v) {
    int r = __builtin_amdgcn_update_dpp(0, __float_as_int(v), CTRL, 0xF, 0xF, true);
    return v + __int_as_float(r);
}

// bf16 round-to-nearest-even helpers
__device__ __forceinline__ unsigned short bf16_rne(float f) {
    unsigned int u = __float_as_uint(f);
    return (unsigned short)((u + 0x7FFFu + ((u >> 16) & 1u)) >> 16);
}
__device__ __forceinline__ unsigned short bf16_hi(float f, float& rem) {
    unsigned int u = __float_as_uint(f);
    unsigned int hb = (u + 0x7FFFu + ((u >> 16) & 1u)) >> 16;
    rem = f - __uint_as_float(hb << 16);
    return (unsigned short)hb;
}

// async global->LDS 16B (wave-uniform LDS base + lane*16)
__device__ __forceinline__ void async_g2l16(const void* g, void* l) {
    __builtin_amdgcn_global_load_lds(
        (const __attribute__((address_space(1))) unsigned int*)g,
        (__attribute__((address_space(3))) unsigned int*)l, 16, 0, 0);
}

// ---------------- conv front: x->bf16 + w_in transpose (gemm2 deps only) --
// [0,768):    bf16 round of x (grid-strided x4)
// [768,1920): transpose+split w_in (768x1536 -> [1536][768] h+l)
__global__ __launch_bounds__(256) void conv_front_k(
    const float* __restrict__ x,
    unsigned short* __restrict__ xh,
    const float* __restrict__ w_in,
    unsigned short* __restrict__ wih, unsigned short* __restrict__ wil)
{
    __shared__ float shmem[32 * 33];
    const int bid = blockIdx.x;
    const int t = threadIdx.x;
    if (bid < 768) {
#pragma unroll
        for (int r = 0; r < 4; ++r) {
            int i = (bid + 768 * r) * 256 + t;
            float4 v = ((const float4*)x)[i];
            ushort4 h;
            h.x = bf16_rne(v.x);
            h.y = bf16_rne(v.y);
            h.z = bf16_rne(v.z);
            h.w = bf16_rne(v.w);
            ((ushort4*)xh)[i] = h;
        }
        return;
    }
    int b2 = bid - 768;
    const int N = 1536, K = 768;
    float (*tile)[33] = (float (*)[33])shmem;
    const int tx = t & 31, ty = t >> 5;
    const int bx = b2 % 48, by = b2 / 48;
    const int n0 = bx * 32, k0 = by * 32;
#pragma unroll
    for (int r = 0; r < 4; ++r)
        tile[ty + r * 8][tx] = w_in[(size_t)(k0 + ty + r * 8) * N + n0 + tx];
    __syncthreads();
#pragma unroll
    for (int r = 0; r < 4; ++r) {
        float v = tile[tx][ty + r * 8];
        float rem;
        unsigned short h = bf16_hi(v, rem);
        size_t o = (size_t)(n0 + ty + r * 8) * K + k0 + tx;
        wih[o] = h;
        wil[o] = bf16_rne(rem);
    }
}

// ---------------- gemm2 + conv-tail fused dispatch ----------------
// blocks [0,768):    xz = silu(x @ in_proj_w)  (128x64 2-term dbuf GEMM,
//                    also emits x_in bf16 h/l for cols<768)
// blocks [768,1537): conv-tail (w_out transpose 576 | W_dt_eff 144 |
//                    w_xp BC cols 48 | bias 1) — independent outputs,
//                    overlapped with the GEMM instead of serialized.
__global__ __launch_bounds__(256, 3) void gemm2t_k(
    const unsigned short* __restrict__ Ah,
    const unsigned short* __restrict__ Bth, const unsigned short* __restrict__ Btl,
    float* __restrict__ C,
    unsigned short* __restrict__ xh, unsigned short* __restrict__ xl,
    const float* __restrict__ w_out,
    unsigned short* __restrict__ woh, unsigned short* __restrict__ wol,
    const float* __restrict__ w_xp,
    const float* __restrict__ w_dt,
    const float* __restrict__ b_dt,
    unsigned short* __restrict__ wbh, unsigned short* __restrict__ wbl,
    float* __restrict__ bias_full)
{
    __shared__ unsigned short smem[2][8192];  // 32 KB; conv tail reuses as float*

    const int t = threadIdx.x;
    const int bid = blockIdx.x;
    const int K = 768, ldc = 1536, nby = 32;

    if (bid < 768) {
        const int wave = t >> 6, lane = t & 63;
        const int bx = bid / nby, by = bid % nby;
        const int bm = by * 128, bn = bx * 64;
        const int mw = (wave >> 1) * 64, nw = (wave & 1) * 32;

        const unsigned short* smat;
        int row0, lmoff;
        if      (wave == 0) { smat = Ah;  row0 = bm;      lmoff = 0; }
        else if (wave == 1) { smat = Ah;  row0 = bm + 64; lmoff = 4096; }
        else if (wave == 2) { smat = Bth; row0 = bn;      lmoff = 8192; }
        else                { smat = Btl; row0 = bn;      lmoff = 12288; }
        const int lr = lane >> 2;
        const int kq = (lane & 3) ^ ((lane >> 3) & 3);
        const unsigned short* gbase = smat + (size_t)(row0 + lr) * K + kq * 8;

        const int la = lane & 15, g4 = lane >> 4;
        const int fo = (g4 ^ ((la >> 1) & 3)) * 8;
        const int aoff = (mw + la) * 32 + fo;
        const int boff = (nw + la) * 32 + fo;

        f32x4 acc[4][2];
#pragma unroll
        for (int i = 0; i < 4; ++i)
#pragma unroll
            for (int j = 0; j < 2; ++j) acc[i][j] = (f32x4){0.f, 0.f, 0.f, 0.f};

        auto stage = [&](int buf, int k0) {
            char* lm = (char*)&smem[buf][0] + lmoff;
            const unsigned short* g = gbase + k0;
#pragma unroll
            for (int j = 0; j < 4; ++j)
                async_g2l16(g + (size_t)j * 16 * K, lm + j * 1024);
        };

        stage(0, 0);
        DRAIN_VMEM();
        __syncthreads();

        for (int k0 = 0; k0 < K; k0 += 32) {
            const int cur = (k0 >> 5) & 1;
            if (k0 + 32 < K) stage(cur ^ 1, k0 + 32);

            const unsigned short* base = &smem[cur][0];
            const unsigned short* pAh = base + aoff;
            const unsigned short* pBh = base + 4096 + boff;
            const unsigned short* pBl = base + 6144 + boff;

            bf16x8 fah[4], fbh[2], fbl[2];
#pragma unroll
            for (int i = 0; i < 4; ++i)
                fah[i] = *(const bf16x8*)(pAh + i * 512);
#pragma unroll
            for (int j = 0; j < 2; ++j) {
                fbh[j] = *(const bf16x8*)(pBh + j * 512);
                fbl[j] = *(const bf16x8*)(pBl + j * 512);
            }
#pragma unroll
            for (int i = 0; i < 4; ++i)
#pragma unroll
                for (int j = 0; j < 2; ++j)
                    acc[i][j] = __builtin_amdgcn_mfma_f32_16x16x32_bf16(fah[i], fbh[j], acc[i][j], 0, 0, 0);
#pragma unroll
            for (int i = 0; i < 4; ++i)
#pragma unroll
                for (int j = 0; j < 2; ++j)
                    acc[i][j] = __builtin_amdgcn_mfma_f32_16x16x32_bf16(fah[i], fbl[j], acc[i][j], 0, 0, 0);
            DRAIN_VMEM();
            __syncthreads();
        }

#pragma unroll
        for (int i = 0; i < 4; ++i) {
            int row = bm + mw + i * 16 + g4 * 4;
#pragma unroll
            for (int j = 0; j < 2; ++j) {
                int col = bn + nw + j * 16 + la;
#pragma unroll
                for (int r = 0; r < 4; ++r) {
                    float v = silu_f(acc[i][j][r]);
                    C[(size_t)(row + r) * ldc + col] = v;
                    if (col < 768) {
                        float rem;
                        unsigned short hh = bf16_hi(v, rem);
                        xh[(size_t)(row + r) * 768 + col] = hh;
                        xl[(size_t)(row + r) * 768 + col] = bf16_rne(rem);
                    }
                }
            }
        }
        return;
    }

    // ---------------- conv tail ----------------
    float* shmem = (float*)&smem[0][0];
    const int tb = bid - 768;
    if (tb < 576) {
        // transpose+split w_out (768x768)
        const int N = 768, K2 = 768;
        float (*tile)[33] = (float (*)[33])shmem;
        const int tx = t & 31, ty = t >> 5;
        const int bx = tb % 24, by = tb / 24;
        const int n0 = bx * 32, k0 = by * 32;
#pragma unroll
        for (int r = 0; r < 4; ++r)
            tile[ty + r * 8][tx] = w_out[(size_t)(k0 + ty + r * 8) * N + n0 + tx];
        __syncthreads();
#pragma unroll
        for (int r = 0; r < 4; ++r) {
            float v = tile[tx][ty + r * 8];
            float rem;
            unsigned short h = bf16_hi(v, rem);
            size_t o = (size_t)(n0 + ty + r * 8) * K2 + k0 + tx;
            woh[o] = h;
            wol[o] = bf16_rne(rem);
        }
        return;
    }
    if (tb < 720) {
        // W_dt_eff = w_xp[:, :48] @ w_dt, 64x64 tile -> wb rows 64..831
        int b4 = tb - 576;
        int bxw = b4 % 12, byw = b4 / 12;
        const int kd0 = byw * 64, dd0 = bxw * 64;
        float* As = shmem;              // [64][49]
        float* Ws = shmem + 64 * 49;    // [48][65]
        {
            int r = t >> 2;
            int c4 = (t & 3) * 4;
#pragma unroll
            for (int s = 0; s < 3; ++s) {
                float4 a = *(const float4*)&w_xp[(size_t)(kd0 + r) * 112 + c4 + 16 * s];
                As[r * 49 + c4 + 16 * s + 0] = a.x;
                As[r * 49 + c4 + 16 * s + 1] = a.y;
                As[r * 49 + c4 + 16 * s + 2] = a.z;
                As[r * 49 + c4 + 16 * s + 3] = a.w;
            }
            int rw = t >> 4;
            int cw = (t & 15) * 4;
#pragma unroll
            for (int s = 0; s < 3; ++s) {
                float4 w = *(const float4*)&w_dt[(size_t)(rw + 16 * s) * 768 + dd0 + cw];
                Ws[(rw + 16 * s) * 65 + cw + 0] = w.x;
                Ws[(rw + 16 * s) * 65 + cw + 1] = w.y;
                Ws[(rw + 16 * s) * 65 + cw + 2] = w.z;
                Ws[(rw + 16 * s) * 65 + cw + 3] = w.w;
            }
        }
        __syncthreads();
        const int ty = t >> 4, tx = t & 15;
        float acc[4][4];
#pragma unroll
        for (int i = 0; i < 4; ++i)
#pragma unroll
            for (int j = 0; j < 4; ++j) acc[i][j] = 0.0f;
        for (int k = 0; k < 48; ++k) {
            float ar[4], wr[4];
#pragma unroll
            for (int i = 0; i < 4; ++i) ar[i] = As[(ty * 4 + i) * 49 + k];
#pragma unroll
            for (int j = 0; j < 4; ++j) wr[j] = Ws[k * 65 + tx * 4 + j];
#pragma unroll
            for (int i = 0; i < 4; ++i)
#pragma unroll
                for (int j = 0; j < 4; ++j)
                    acc[i][j] = fmaf(ar[i], wr[j], acc[i][j]);
        }
        __syncthreads();
        float* Ot = shmem;              // [64][65]
#pragma unroll
        for (int i = 0; i < 4; ++i)
#pragma unroll
            for (int j = 0; j < 4; ++j)
                Ot[(tx * 4 + j) * 65 + ty * 4 + i] = acc[i][j];
        __syncthreads();
        int dl = t >> 2, c0 = (t & 3) * 16;
#pragma unroll
        for (int k = 0; k < 16; ++k) {
            float v = Ot[dl * 65 + c0 + k];
            float rem;
            unsigned short h = bf16_hi(v, rem);
            size_t o = (size_t)(64 + dd0 + dl) * 768 + kd0 + c0 + k;
            wbh[o] = h;
            wbl[o] = bf16_rne(rem);
        }
        return;
    }
    if (tb < 768) {
        // transpose+split w_xp cols 48..111 -> wb rows 0..63
        int b5 = tb - 720;
        int bxb = b5 & 1, byb = b5 >> 1;
        const int n0 = bxb * 32, k0 = byb * 32;
        float (*tile)[33] = (float (*)[33])shmem;
        const int tx = t & 31, ty = t >> 5;
#pragma unroll
        for (int r = 0; r < 4; ++r)
            tile[ty + r * 8][tx] = w_xp[(size_t)(k0 + ty + r * 8) * 112 + 48 + n0 + tx];
        __syncthreads();
#pragma unroll
        for (int r = 0; r < 4; ++r) {
            float v = tile[tx][ty + r * 8];
            float rem;
            unsigned short h = bf16_hi(v, rem);
            size_t o = (size_t)(n0 + ty + r * 8) * 768 + k0 + tx;
            wbh[o] = h;
            wbl[o] = bf16_rne(rem);
        }
        return;
    }
    // bias_full
#pragma unroll
    for (int i = 0; i < 4; ++i) {
        int idx = t + 256 * i;
        if (idx < 896)
            bias_full[idx] = (idx >= 64 && idx < 832) ? b_dt[idx - 64] : 0.0f;
    }
}

// ---------------- 3-term split-bf16 MFMA GEMM, 128x32 tile, dbuf ----------
// BN=32: grid 896 blocks (3.5/CU) vs v9's 448 (1.75/CU).
__global__ __launch_bounds__(256, 3) void mgemm3_k(
    const unsigned short* __restrict__ Ahp, const unsigned short* __restrict__ Alp,
    const unsigned short* __restrict__ Bth, const unsigned short* __restrict__ Btl,
    const float* __restrict__ bias,
    float* __restrict__ C, int K, int ldc, int nby)
{
    __shared__ unsigned short smem[2][10240];  // dbuf x (Ah 4096 | Al 4096 | Bh 1024 | Bl 1024) ushorts

    const int t = threadIdx.x;
    const int wave = t >> 6, lane = t & 63;
    const int bx = blockIdx.x / nby, by = blockIdx.x % nby;
    const int bm = by * 128, bn = bx * 32;
    const int mw = (wave >> 1) * 64, nw = (wave & 1) * 16;

    // staging: wave0 Ah (8 inst), wave1 Al (8), wave2 Bh (2), wave3 Bl (2)
    const unsigned short* smat;
    int row0, ninst, lmoff;
    if      (wave == 0) { smat = Ahp; row0 = bm; ninst = 8; lmoff = 0; }
    else if (wave == 1) { smat = Alp; row0 = bm; ninst = 8; lmoff = 8192; }
    else if (wave == 2) { smat = Bth; row0 = bn; ninst = 2; lmoff = 16384; }
    else                { smat = Btl; row0 = bn; ninst = 2; lmoff = 18432; }
    const int lr = lane >> 2;
    const int kq = (lane & 3) ^ ((lane >> 3) & 3);
    const unsigned short* gbase = smat + (size_t)(row0 + lr) * K + kq * 8;

    const int la = lane & 15, g4 = lane >> 4;
    const int fo = (g4 ^ ((la >> 1) & 3)) * 8;
    const int aoff = (mw + la) * 32 + fo;
    const int boff = (nw + la) * 32 + fo;

    f32x4 acc[4];
#pragma unroll
    for (int i = 0; i < 4; ++i) acc[i] = (f32x4){0.f, 0.f, 0.f, 0.f};

    auto stage = [&](int buf, int k0) {
        char* lm = (char*)&smem[buf][0] + lmoff;
        const unsigned short* g = gbase + k0;
        if (ninst == 8) {
#pragma unroll
            for (int j = 0; j < 8; ++j)
                async_g2l16(g + (size_t)j * 16 * K, lm + j * 1024);
        } else {
#pragma unroll
            for (int j = 0; j < 2; ++j)
                async_g2l16(g + (size_t)j * 16 * K, lm + j * 1024);
        }
    };

    stage(0, 0);
    DRAIN_VMEM();
    __syncthreads();

    for (int k0 = 0; k0 < K; k0 += 32) {
        const int cur = (k0 >> 5) & 1;
        if (k0 + 32 < K) stage(cur ^ 1, k0 + 32);

        const unsigned short* base = &smem[cur][0];
        const unsigned short* pAh = base + aoff;
        const unsigned short* pAl = base + 4096 + aoff;
        const unsigned short* pBh = base + 8192 + boff;
        const unsigned short* pBl = base + 9216 + boff;

        bf16x8 fah[4], fal[4], fbh, fbl;
#pragma unroll
        for (int i = 0; i < 4; ++i) {
            fah[i] = *(const bf16x8*)(pAh + i * 512);
            fal[i] = *(const bf16x8*)(pAl + i * 512);
        }
        fbh = *(const bf16x8*)(pBh);
        fbl = *(const bf16x8*)(pBl);
#pragma unroll
        for (int i = 0; i < 4; ++i)
            acc[i] = __builtin_amdgcn_mfma_f32_16x16x32_bf16(fah[i], fbh, acc[i], 0, 0, 0);
#pragma unroll
        for (int i = 0; i < 4; ++i)
            acc[i] = __builtin_amdgcn_mfma_f32_16x16x32_bf16(fah[i], fbl, acc[i], 0, 0, 0);
#pragma unroll
        for (int i = 0; i < 4; ++i)
            acc[i] = __builtin_amdgcn_mfma_f32_16x16x32_bf16(fal[i], fbh, acc[i], 0, 0, 0);
        DRAIN_VMEM();
        __syncthreads();
    }

#pragma unroll
    for (int i = 0; i < 4; ++i) {
        int row = bm + mw + i * 16 + g4 * 4;
        int col = bn + nw + la;
        float bz = bias[col];
#pragma unroll
        for (int r = 0; r < 4; ++r) {
            float v = acc[i][r] + bz;
            if (col >= 64) v = softplus_f(v);
            C[(size_t)(row + r) * ldc + col] = v;
        }
    }
}

// ---------------- 2-term split-bf16 MFMA GEMM, 128x32 tile, dbuf ----------
// (out-projection) BN=32: grid 768 blocks (3/CU) vs v9's 384 (1.5/CU).
__global__ __launch_bounds__(256, 3) void mgemm_out_k(
    const unsigned short* __restrict__ Ah,
    const unsigned short* __restrict__ Bth, const unsigned short* __restrict__ Btl,
    const float* __restrict__ bias,
    float* __restrict__ C, int K, int ldc, int nby)
{
    __shared__ unsigned short smem[2][6144];  // dbuf x (Ah 4096 | Bh 1024 | Bl 1024) ushorts

    const int t = threadIdx.x;
    const int wave = t >> 6, lane = t & 63;
    const int bx = blockIdx.x / nby, by = blockIdx.x % nby;
    const int bm = by * 128, bn = bx * 32;
    const int mw = (wave >> 1) * 64, nw = (wave & 1) * 16;

    // staging: wave0 Ah rows 0-63 (4), wave1 Ah rows 64-127 (4),
    //          wave2 Bh (2), wave3 Bl (2)
    const unsigned short* smat;
    int row0, ninst, lmoff;
    if      (wave == 0) { smat = Ah;  row0 = bm;      ninst = 4; lmoff = 0; }
    else if (wave == 1) { smat = Ah;  row0 = bm + 64; ninst = 4; lmoff = 4096; }
    else if (wave == 2) { smat = Bth; row0 = bn;      ninst = 2; lmoff = 8192; }
    else                { smat = Btl; row0 = bn;      ninst = 2; lmoff = 10240; }
    const int lr = lane >> 2;
    const int kq = (lane & 3) ^ ((lane >> 3) & 3);
    const unsigned short* gbase = smat + (size_t)(row0 + lr) * K + kq * 8;

    const int la = lane & 15, g4 = lane >> 4;
    const int fo = (g4 ^ ((la >> 1) & 3)) * 8;
    const int aoff = (mw + la) * 32 + fo;
    const int boff = (nw + la) * 32 + fo;

    f32x4 acc[4];
#pragma unroll
    for (int i = 0; i < 4; ++i) acc[i] = (f32x4){0.f, 0.f, 0.f, 0.f};

    auto stage = [&](int buf, int k0) {
        char* lm = (char*)&smem[buf][0] + lmoff;
        const unsigned short* g = gbase + k0;
        if (ninst == 4) {
#pragma unroll
            for (int j = 0; j < 4; ++j)
                async_g2l16(g + (size_t)j * 16 * K, lm + j * 1024);
        } else {
#pragma unroll
            for (int j = 0; j < 2; ++j)
                async_g2l16(g + (size_t)j * 16 * K, lm + j * 1024);
        }
    };

    stage(0, 0);
    DRAIN_VMEM();
    __syncthreads();

    for (int k0 = 0; k0 < K; k0 += 32) {
        const int cur = (k0 >> 5) & 1;
        if (k0 + 32 < K) stage(cur ^ 1, k0 + 32);

        const unsigned short* base = &smem[cur][0];
        const unsigned short* pAh = base + aoff;
        const unsigned short* pBh = base + 4096 + boff;
        const unsigned short* pBl = base + 5120 + boff;

        bf16x8 fah[4], fbh, fbl;
#pragma unroll
        for (int i = 0; i < 4; ++i)
            fah[i] = *(const bf16x8*)(pAh + i * 512);
        fbh = *(const bf16x8*)(pBh);
        fbl = *(const bf16x8*)(pBl);
#pragma unroll
        for (int i = 0; i < 4; ++i)
            acc[i] = __builtin_amdgcn_mfma_f32_16x16x32_bf16(fah[i], fbh, acc[i], 0, 0, 0);
#pragma unroll
        for (int i = 0; i < 4; ++i)
            acc[i] = __builtin_amdgcn_mfma_f32_16x16x32_bf16(fah[i], fbl, acc[i], 0, 0, 0);
        DRAIN_VMEM();
        __syncthreads();
    }

#pragma unroll
    for (int i = 0; i < 4; ++i) {
        int row = bm + mw + i * 16 + g4 * 4;
        int col = bn + nw + la;
        float bz = bias[col];
#pragma unroll
        for (int r = 0; r < 4; ++r)
            C[(size_t)(row + r) * ldc + col] = acc[i][r] + bz;
    }
}

// ---------------- sequential fractal scan (v8-verbatim, 97.2µs) -----------
#define L_LEN 1024
#define CH 32
#define NCH (L_LEN / CH)
#define CHP (CH + 4)

__global__ __launch_bounds__(512) void scan_k(
    const float* __restrict__ xz,    // M x 1536 (silu applied to both halves)
    const float* __restrict__ bcdt,  // M x 896 (BC | dt)
    const float* __restrict__ A_log,
    unsigned short* __restrict__ ybh)  // M x 768 bf16 of y*silu(z)
{
    __shared__ float xdt_t[2][16][CHP];
    __shared__ float ds_t[2][16][CHP];
    __shared__ float B0s[2][16][CHP];
    __shared__ float B1s[2][16][CHP];
    __shared__ float C0s[2][16][CHP];
    __shared__ float C1s[2][16][CHP];
    __shared__ float ysp[2][CH][16][8];

    const int t  = threadIdx.x;
    const int b  = blockIdx.y;
    const int d0 = blockIdx.x * 16;
    const size_t rowbase = (size_t)b * L_LEN;
    const bool is_chain = (t < 256);

    const int n  = t & 15;
    const int dl = (t >> 4) & 15;
    const int np = n >> 1;
    float negAl2e = 0.0f, h0 = 0.0f, h1 = 0.0f;
    float s2 = 1.0f, lT = 0.0f;
    if (is_chain) {
        negAl2e = -__expf(A_log[n]) * LOG2E;
        float phase = 6.283185307179586f * (float)n / 16.0f;
        h0 = 0.01f * cosf(phase);
        h1 = 0.01f * sinf(phase);
        lT = LOG2F(fmaf(h0, h0, fmaf(h1, h1, 1e-8f)));   // s2=1 -> lT = lq0
    }

    const int t2 = t - 256;
    const int hl = t2 >> 2;
    const int hf = (t2 & 3) * 4;

    auto stage = [&](int cc) {
        const int bi = cc & 1;
        if (t2 < 128) {
            size_t row = rowbase + cc * CH + hl;
            float4 rx = *(const float4*)&xz[row * 1536 + d0 + hf];
            float4 rd = *(const float4*)&bcdt[row * 896 + 64 + d0 + hf];
            xdt_t[bi][hf + 0][hl] = rx.x * rd.x;
            xdt_t[bi][hf + 1][hl] = rx.y * rd.y;
            xdt_t[bi][hf + 2][hl] = rx.z * rd.z;
            xdt_t[bi][hf + 3][hl] = rx.w * rd.w;
            ds_t[bi][hf + 0][hl] = rd.x;
            ds_t[bi][hf + 1][hl] = rd.y;
            ds_t[bi][hf + 2][hl] = rd.z;
            ds_t[bi][hf + 3][hl] = rd.w;
        }
#pragma unroll
        for (int i = 0; i < 2; ++i) {
            int idx = t2 + 256 * i;
            int lb = idx >> 4, j4 = (idx & 15) * 4;
            float4 rbc = *(const float4*)&bcdt[(rowbase + cc * CH + lb) * 896 + j4];
            if (j4 < 32) {
                int nn = j4 >> 1;
                B0s[bi][nn][lb]     = rbc.x;
                B1s[bi][nn][lb]     = rbc.y;
                B0s[bi][nn + 1][lb] = rbc.z;
                B1s[bi][nn + 1][lb] = rbc.w;
            } else {
                int nn = (j4 - 32) >> 1;
                C0s[bi][nn][lb]     = rbc.x;
                C1s[bi][nn][lb]     = rbc.y;
                C0s[bi][nn + 1][lb] = rbc.z;
                C1s[bi][nn + 1][lb] = rbc.w;
            }
        }
    };

    auto store_y = [&](int cs) {
        if (t2 >= 128) return;
        const int bi = cs & 1;
        size_t row = rowbase + cs * CH + hl;
        float4 zq = *(const float4*)&xz[row * 1536 + 768 + d0 + hf];
        float yr[4];
#pragma unroll
        for (int j = 0; j < 4; ++j) {
            float4 p0 = *(const float4*)&ysp[bi][hl][hf + j][0];
            float4 p1 = *(const float4*)&ysp[bi][hl][hf + j][4];
            yr[j] = ((p0.x + p0.y) + (p0.z + p0.w)) + ((p1.x + p1.y) + (p1.z + p1.w));
        }
        ushort4 hh;
        hh.x = bf16_rne(yr[0] * zq.x);
        hh.y = bf16_rne(yr[1] * zq.y);
        hh.z = bf16_rne(yr[2] * zq.z);
        hh.w = bf16_rne(yr[3] * zq.w);
        *(ushort4*)&ybh[row * 768 + d0 + hf] = hh;
    };

    if (!is_chain) stage(0);
    __syncthreads();

    for (int c = 0; c < NCH; ++c) {
        if (is_chain) {
            __builtin_amdgcn_s_setprio(1);
            const int bi = c & 1;
            const float* xr  = &xdt_t[bi][dl][0];
            const float* dr  = &ds_t[bi][dl][0];
            const float* b0r = &B0s[bi][n][0];
            const float* b1r = &B1s[bi][n][0];
            const float* c0r = &C0s[bi][n][0];
            const float* c1r = &C1s[bi][n][0];

            float4 px  = *(const float4*)(xr);
            float4 pd  = *(const float4*)(dr);
            float4 pb0 = *(const float4*)(b0r);
            float4 pb1 = *(const float4*)(b1r);
            float4 pc0 = *(const float4*)(c0r);
            float4 pc1 = *(const float4*)(c1r);

            for (int l4 = 0; l4 < CH; l4 += 4) {
                float4 cx = px, cd = pd, cb0 = pb0, cb1 = pb1, cc0 = pc0, cc1 = pc1;
                if (l4 + 4 < CH) {
                    px  = *(const float4*)(xr  + l4 + 4);
                    pd  = *(const float4*)(dr  + l4 + 4);
                    pb0 = *(const float4*)(b0r + l4 + 4);
                    pb1 = *(const float4*)(b1r + l4 + 4);
                    pc0 = *(const float4*)(c0r + l4 + 4);
                    pc1 = *(const float4*)(c1r + l4 + 4);
                }
                const float xv[4]  = {cx.x,  cx.y,  cx.z,  cx.w};
                const float dv[4]  = {cd.x,  cd.y,  cd.z,  cd.w};
                const float C0v[4] = {cc0.x, cc0.y, cc0.z, cc0.w};
                const float C1v[4] = {cc1.x, cc1.y, cc1.z, cc1.w};

                // off-path hoists: coefficient and B*x*dt for the 4 steps
                float cfv[4], bx0[4], bx1[4];
                const float B0v[4] = {cb0.x, cb0.y, cb0.z, cb0.w};
                const float B1v[4] = {cb1.x, cb1.y, cb1.z, cb1.w};
#pragma unroll
                for (int u = 0; u < 4; ++u) {
                    cfv[u] = fmaf(EXP2F(dv[u] * negAl2e), -0.25f, 0.25f);
                    bx0[u] = B0v[u] * xv[u];
                    bx1[u] = B1v[u] * xv[u];
                }

#pragma unroll
                for (int u = 0; u < 4; ++u) {
                    float g = s2 * EXP2F(cfv[u] * lT);
                    h0 = fmaf(h0, g, bx0[u]);
                    h1 = fmaf(h1, g, bx1[u]);
                    float q  = fmaf(h0, h0, fmaf(h1, h1, 1e-8f));
                    float q2 = q * q;                       // Estrin [3/3] Pade
                    float num = fmaf(q2, q + 378.0f,              fmaf(17325.0f, q, 135135.0f));
                    float den = fmaf(q2, fmaf(28.0f, q, 3150.0f), fmaf(62370.0f, q, 135135.0f));
                    s2 = num * RCPF(den);
                    lT = LOG2F(s2 * s2 * q);                // log2(tanh^2 m)

                    float yv = s2 * fmaf(C0v[u], h0, C1v[u] * h1);
                    yv = dpp_add<0xB1>(yv);                 // pair sum
                    if ((n & 1) == 0) ysp[bi][l4 + u][dl][np] = yv;
                }
            }
            __builtin_amdgcn_s_setprio(0);
        } else {
            if (c + 1 < NCH) stage(c + 1);
            if (c >= 1) store_y(c - 1);
        }
        __syncthreads();
    }
    if (!is_chain) store_y(NCH - 1);
}

// ---------------- launcher ----------------
extern "C" void kernel_launch(void* const* d_in, const int* in_sizes, int n_in,
                              void* d_out, int out_size, void* d_ws, size_t ws_size,
                              hipStream_t stream)
{
    const float* x     = (const float*)d_in[0];
    const float* w_in  = (const float*)d_in[1];
    const float* w_xp  = (const float*)d_in[2];
    const float* w_dt  = (const float*)d_in[3];
    const float* b_dt  = (const float*)d_in[4];
    const float* w_out = (const float*)d_in[5];
    const float* b_out = (const float*)d_in[6];
    const float* A_log = (const float*)d_in[7];
    float* out = (float*)d_out;

    const int M = 4096;
    float* xz        = (float*)d_ws;                       // M*1536 f32
    float* bcdt      = xz + (size_t)M * 1536;              // M*896  f32
    float* bias_full = bcdt + (size_t)M * 896;             // 896    f32
    unsigned short* ah   = (unsigned short*)(bias_full + 896);  // M*768
    unsigned short* ybh  = ah   + (size_t)M * 768;         // M*768
    unsigned short* xinh = ybh  + (size_t)M * 768;         // M*768
    unsigned short* xinl = xinh + (size_t)M * 768;         // M*768
    unsigned short* wh   = xinl + (size_t)M * 768;         // 1536*768
    unsigned short* wl   = wh   + (size_t)1536 * 768;
    unsigned short* voh  = wl   + (size_t)1536 * 768;      // 768*768
    unsigned short* vol  = voh  + (size_t)768 * 768;
    unsigned short* wbh  = vol  + (size_t)768 * 768;       // 896*768
    unsigned short* wbl  = wbh  + (size_t)896 * 768;

    dim3 blk(256);

    // 1) conv front: x bf16 + w_in transpose (only what gemm2 needs)
    conv_front_k<<<dim3(1920), blk, 0, stream>>>(x, ah, w_in, wh, wl);

    // 2) gemm2 (768 blocks) + conv tail (769 blocks) fused dispatch
    gemm2t_k<<<dim3(1537), blk, 0, stream>>>(
        ah, wh, wl, xz, xinh, xinl,
        w_out, voh, vol, w_xp, w_dt, b_dt, wbh, wbl, bias_full);

    // 3) bcdt = [x_in @ w_xp[:,48:] | softplus(x_in @ W_dt_eff + b_dt)]
    //    BN=32: 28 x 32 = 896 blocks (3.5/CU)
    mgemm3_k<<<dim3(28 * 32), blk, 0, stream>>>(
        xinh, xinl, wbh, wbl, bias_full, bcdt, 768, 896, 32);

    // 4) scan -> ybh = bf16(y_scan * silu(z))
    scan_k<<<dim3(48, 4), dim3(512), 0, stream>>>(xz, bcdt, A_log, ybh);

    // 5) out = yb @ out_proj_w + b_out   BN=32: 24 x 32 = 768 blocks (3/CU)
    mgemm_out_k<<<dim3(24 * 32), blk, 0, stream>>>(
        ybh, voh, vol, b_out, out, 768, 768, 32);
}

// Round 11
// 252.276 us; speedup vs baseline: 1.0196x; 1.0173x over previous
//
#include <hip/hip_runtime.h>
#include <math.h>

// ---------------- fast transcendental helpers ----------------
#if __has_builtin(__builtin_amdgcn_exp2f)
#define EXP2F(x) __builtin_amdgcn_exp2f(x)
#else
#define EXP2F(x) exp2f(x)
#endif
#if __has_builtin(__builtin_amdgcn_logf)
#define LOG2F(x) __builtin_amdgcn_logf(x)
#else
#define LOG2F(x) log2f(x)
#endif
#if __has_builtin(__builtin_amdgcn_rcpf)
#define RCPF(x) __builtin_amdgcn_rcpf(x)
#else
#define RCPF(x) (1.0f / (x))
#endif

#define LOG2E 1.4426950408889634f

// Drain this wave's global_load_lds DMAs. REQUIRED before the barrier that
// publishes a freshly staged LDS buffer (v7 post-timing race: compiler does
// not conservatively drain vmcnt at __syncthreads in the dbuf shape).
#define DRAIN_VMEM() asm volatile("s_waitcnt vmcnt(0)" ::: "memory")

typedef __bf16 bf16x8 __attribute__((ext_vector_type(8)));
typedef float f32x4 __attribute__((ext_vector_type(4)));

__device__ __forceinline__ float silu_f(float v) {
    return v * RCPF(1.0f + EXP2F(-v * LOG2E));
}
__device__ __forceinline__ float softplus_f(float v) {
    return fmaxf(v, 0.0f) + log1pf(__expf(-fabsf(v)));
}

// quad_perm DPP add. 0xB1 = swap pairs -> pair sum.
template <int CTRL>
__device__ __forceinline__ float dpp_add(float v) {
    int r = __builtin_amdgcn_update_dpp(0, __float_as_int(v), CTRL, 0xF, 0xF, true);
    return v + __int_as_float(r);
}

// bf16 round-to-nearest-even helpers
__device__ __forceinline__ unsigned short bf16_rne(float f) {
    unsigned int u = __float_as_uint(f);
    return (unsigned short)((u + 0x7FFFu + ((u >> 16) & 1u)) >> 16);
}
__device__ __forceinline__ unsigned short bf16_hi(float f, float& rem) {
    unsigned int u = __float_as_uint(f);
    unsigned int hb = (u + 0x7FFFu + ((u >> 16) & 1u)) >> 16;
    rem = f - __uint_as_float(hb << 16);
    return (unsigned short)hb;
}

// async global->LDS 16B (wave-uniform LDS base + lane*16)
__device__ __forceinline__ void async_g2l16(const void* g, void* l) {
    __builtin_amdgcn_global_load_lds(
        (const __attribute__((address_space(1))) unsigned int*)g,
        (__attribute__((address_space(3))) unsigned int*)l, 16, 0, 0);
}

// ---------------- conv front: x->bf16 + w_in transpose (gemm2 deps only) --
__global__ __launch_bounds__(256) void conv_front_k(
    const float* __restrict__ x,
    unsigned short* __restrict__ xh,
    const float* __restrict__ w_in,
    unsigned short* __restrict__ wih, unsigned short* __restrict__ wil)
{
    __shared__ float shmem[32 * 33];
    const int bid = blockIdx.x;
    const int t = threadIdx.x;
    if (bid < 768) {
#pragma unroll
        for (int r = 0; r < 4; ++r) {
            int i = (bid + 768 * r) * 256 + t;
            float4 v = ((const float4*)x)[i];
            ushort4 h;
            h.x = bf16_rne(v.x);
            h.y = bf16_rne(v.y);
            h.z = bf16_rne(v.z);
            h.w = bf16_rne(v.w);
            ((ushort4*)xh)[i] = h;
        }
        return;
    }
    int b2 = bid - 768;
    const int N = 1536, K = 768;
    float (*tile)[33] = (float (*)[33])shmem;
    const int tx = t & 31, ty = t >> 5;
    const int bx = b2 % 48, by = b2 / 48;
    const int n0 = bx * 32, k0 = by * 32;
#pragma unroll
    for (int r = 0; r < 4; ++r)
        tile[ty + r * 8][tx] = w_in[(size_t)(k0 + ty + r * 8) * N + n0 + tx];
    __syncthreads();
#pragma unroll
    for (int r = 0; r < 4; ++r) {
        float v = tile[tx][ty + r * 8];
        float rem;
        unsigned short h = bf16_hi(v, rem);
        size_t o = (size_t)(n0 + ty + r * 8) * K + k0 + tx;
        wih[o] = h;
        wil[o] = bf16_rne(rem);
    }
}

// ---------------- gemm2 + conv-tail fused dispatch ----------------
// blocks [0,768):    xz = silu(x @ in_proj_w)  (128x64 2-term dbuf GEMM,
//                    also emits x_in bf16 h/l for cols<768).
//                    v12: z-half tiles (bn>=768) use 1-term (Ah*Bh only) —
//                    z only feeds silu(z)*y which is bf16-rounded anyway;
//                    adds a ~2^-9 relative source, inside the error budget.
// blocks [768,1537): conv-tail (w_out transpose 576 | W_dt_eff 144 |
//                    w_xp BC cols 48 | bias 1)
__global__ __launch_bounds__(256, 3) void gemm2t_k(
    const unsigned short* __restrict__ Ah,
    const unsigned short* __restrict__ Bth, const unsigned short* __restrict__ Btl,
    float* __restrict__ C,
    unsigned short* __restrict__ xh, unsigned short* __restrict__ xl,
    const float* __restrict__ w_out,
    unsigned short* __restrict__ woh, unsigned short* __restrict__ wol,
    const float* __restrict__ w_xp,
    const float* __restrict__ w_dt,
    const float* __restrict__ b_dt,
    unsigned short* __restrict__ wbh, unsigned short* __restrict__ wbl,
    float* __restrict__ bias_full)
{
    __shared__ unsigned short smem[2][8192];  // 32 KB; conv tail reuses as float*

    const int t = threadIdx.x;
    const int bid = blockIdx.x;
    const int K = 768, ldc = 1536, nby = 32;

    if (bid < 768) {
        const int wave = t >> 6, lane = t & 63;
        const int bx = bid / nby, by = bid % nby;
        const int bm = by * 128, bn = bx * 64;
        const int mw = (wave >> 1) * 64, nw = (wave & 1) * 32;
        const bool zh = (bn >= 768);   // z-half: 1-term

        const unsigned short* smat;
        int row0, lmoff;
        if      (wave == 0) { smat = Ah;  row0 = bm;      lmoff = 0; }
        else if (wave == 1) { smat = Ah;  row0 = bm + 64; lmoff = 4096; }
        else if (wave == 2) { smat = Bth; row0 = bn;      lmoff = 8192; }
        else                { smat = Btl; row0 = bn;      lmoff = 12288; }
        const bool skipstage = zh && (wave == 3);   // no Bl needed for z tiles
        const int lr = lane >> 2;
        const int kq = (lane & 3) ^ ((lane >> 3) & 3);
        const unsigned short* gbase = smat + (size_t)(row0 + lr) * K + kq * 8;

        const int la = lane & 15, g4 = lane >> 4;
        const int fo = (g4 ^ ((la >> 1) & 3)) * 8;
        const int aoff = (mw + la) * 32 + fo;
        const int boff = (nw + la) * 32 + fo;

        f32x4 acc[4][2];
#pragma unroll
        for (int i = 0; i < 4; ++i)
#pragma unroll
            for (int j = 0; j < 2; ++j) acc[i][j] = (f32x4){0.f, 0.f, 0.f, 0.f};

        auto stage = [&](int buf, int k0) {
            char* lm = (char*)&smem[buf][0] + lmoff;
            const unsigned short* g = gbase + k0;
#pragma unroll
            for (int j = 0; j < 4; ++j)
                async_g2l16(g + (size_t)j * 16 * K, lm + j * 1024);
        };

        if (!skipstage) stage(0, 0);
        DRAIN_VMEM();
        __syncthreads();

        for (int k0 = 0; k0 < K; k0 += 32) {
            const int cur = (k0 >> 5) & 1;
            if (k0 + 32 < K && !skipstage) stage(cur ^ 1, k0 + 32);

            const unsigned short* base = &smem[cur][0];
            const unsigned short* pAh = base + aoff;
            const unsigned short* pBh = base + 4096 + boff;
            const unsigned short* pBl = base + 6144 + boff;

            bf16x8 fah[4], fbh[2], fbl[2];
#pragma unroll
            for (int i = 0; i < 4; ++i)
                fah[i] = *(const bf16x8*)(pAh + i * 512);
#pragma unroll
            for (int j = 0; j < 2; ++j)
                fbh[j] = *(const bf16x8*)(pBh + j * 512);
            if (!zh) {
#pragma unroll
                for (int j = 0; j < 2; ++j)
                    fbl[j] = *(const bf16x8*)(pBl + j * 512);
            }
#pragma unroll
            for (int i = 0; i < 4; ++i)
#pragma unroll
                for (int j = 0; j < 2; ++j)
                    acc[i][j] = __builtin_amdgcn_mfma_f32_16x16x32_bf16(fah[i], fbh[j], acc[i][j], 0, 0, 0);
            if (!zh) {
#pragma unroll
                for (int i = 0; i < 4; ++i)
#pragma unroll
                    for (int j = 0; j < 2; ++j)
                        acc[i][j] = __builtin_amdgcn_mfma_f32_16x16x32_bf16(fah[i], fbl[j], acc[i][j], 0, 0, 0);
            }
            DRAIN_VMEM();
            __syncthreads();
        }

#pragma unroll
        for (int i = 0; i < 4; ++i) {
            int row = bm + mw + i * 16 + g4 * 4;
#pragma unroll
            for (int j = 0; j < 2; ++j) {
                int col = bn + nw + j * 16 + la;
#pragma unroll
                for (int r = 0; r < 4; ++r) {
                    float v = silu_f(acc[i][j][r]);
                    C[(size_t)(row + r) * ldc + col] = v;
                    if (col < 768) {
                        float rem;
                        unsigned short hh = bf16_hi(v, rem);
                        xh[(size_t)(row + r) * 768 + col] = hh;
                        xl[(size_t)(row + r) * 768 + col] = bf16_rne(rem);
                    }
                }
            }
        }
        return;
    }

    // ---------------- conv tail ----------------
    float* shmem = (float*)&smem[0][0];
    const int tb = bid - 768;
    if (tb < 576) {
        // transpose+split w_out (768x768)
        const int N = 768, K2 = 768;
        float (*tile)[33] = (float (*)[33])shmem;
        const int tx = t & 31, ty = t >> 5;
        const int bx = tb % 24, by = tb / 24;
        const int n0 = bx * 32, k0 = by * 32;
#pragma unroll
        for (int r = 0; r < 4; ++r)
            tile[ty + r * 8][tx] = w_out[(size_t)(k0 + ty + r * 8) * N + n0 + tx];
        __syncthreads();
#pragma unroll
        for (int r = 0; r < 4; ++r) {
            float v = tile[tx][ty + r * 8];
            float rem;
            unsigned short h = bf16_hi(v, rem);
            size_t o = (size_t)(n0 + ty + r * 8) * K2 + k0 + tx;
            woh[o] = h;
            wol[o] = bf16_rne(rem);
        }
        return;
    }
    if (tb < 720) {
        // W_dt_eff = w_xp[:, :48] @ w_dt, 64x64 tile -> wb rows 64..831
        int b4 = tb - 576;
        int bxw = b4 % 12, byw = b4 / 12;
        const int kd0 = byw * 64, dd0 = bxw * 64;
        float* As = shmem;              // [64][49]
        float* Ws = shmem + 64 * 49;    // [48][65]
        {
            int r = t >> 2;
            int c4 = (t & 3) * 4;
#pragma unroll
            for (int s = 0; s < 3; ++s) {
                float4 a = *(const float4*)&w_xp[(size_t)(kd0 + r) * 112 + c4 + 16 * s];
                As[r * 49 + c4 + 16 * s + 0] = a.x;
                As[r * 49 + c4 + 16 * s + 1] = a.y;
                As[r * 49 + c4 + 16 * s + 2] = a.z;
                As[r * 49 + c4 + 16 * s + 3] = a.w;
            }
            int rw = t >> 4;
            int cw = (t & 15) * 4;
#pragma unroll
            for (int s = 0; s < 3; ++s) {
                float4 w = *(const float4*)&w_dt[(size_t)(rw + 16 * s) * 768 + dd0 + cw];
                Ws[(rw + 16 * s) * 65 + cw + 0] = w.x;
                Ws[(rw + 16 * s) * 65 + cw + 1] = w.y;
                Ws[(rw + 16 * s) * 65 + cw + 2] = w.z;
                Ws[(rw + 16 * s) * 65 + cw + 3] = w.w;
            }
        }
        __syncthreads();
        const int ty = t >> 4, tx = t & 15;
        float acc[4][4];
#pragma unroll
        for (int i = 0; i < 4; ++i)
#pragma unroll
            for (int j = 0; j < 4; ++j) acc[i][j] = 0.0f;
        for (int k = 0; k < 48; ++k) {
            float ar[4], wr[4];
#pragma unroll
            for (int i = 0; i < 4; ++i) ar[i] = As[(ty * 4 + i) * 49 + k];
#pragma unroll
            for (int j = 0; j < 4; ++j) wr[j] = Ws[k * 65 + tx * 4 + j];
#pragma unroll
            for (int i = 0; i < 4; ++i)
#pragma unroll
                for (int j = 0; j < 4; ++j)
                    acc[i][j] = fmaf(ar[i], wr[j], acc[i][j]);
        }
        __syncthreads();
        float* Ot = shmem;              // [64][65]
#pragma unroll
        for (int i = 0; i < 4; ++i)
#pragma unroll
            for (int j = 0; j < 4; ++j)
                Ot[(tx * 4 + j) * 65 + ty * 4 + i] = acc[i][j];
        __syncthreads();
        int dl = t >> 2, c0 = (t & 3) * 16;
#pragma unroll
        for (int k = 0; k < 16; ++k) {
            float v = Ot[dl * 65 + c0 + k];
            float rem;
            unsigned short h = bf16_hi(v, rem);
            size_t o = (size_t)(64 + dd0 + dl) * 768 + kd0 + c0 + k;
            wbh[o] = h;
            wbl[o] = bf16_rne(rem);
        }
        return;
    }
    if (tb < 768) {
        // transpose+split w_xp cols 48..111 -> wb rows 0..63
        int b5 = tb - 720;
        int bxb = b5 & 1, byb = b5 >> 1;
        const int n0 = bxb * 32, k0 = byb * 32;
        float (*tile)[33] = (float (*)[33])shmem;
        const int tx = t & 31, ty = t >> 5;
#pragma unroll
        for (int r = 0; r < 4; ++r)
            tile[ty + r * 8][tx] = w_xp[(size_t)(k0 + ty + r * 8) * 112 + 48 + n0 + tx];
        __syncthreads();
#pragma unroll
        for (int r = 0; r < 4; ++r) {
            float v = tile[tx][ty + r * 8];
            float rem;
            unsigned short h = bf16_hi(v, rem);
            size_t o = (size_t)(n0 + ty + r * 8) * 768 + k0 + tx;
            wbh[o] = h;
            wbl[o] = bf16_rne(rem);
        }
        return;
    }
    // bias_full
#pragma unroll
    for (int i = 0; i < 4; ++i) {
        int idx = t + 256 * i;
        if (idx < 896)
            bias_full[idx] = (idx >= 64 && idx < 832) ? b_dt[idx - 64] : 0.0f;
    }
}

// ---------------- 3-term split-bf16 MFMA GEMM, 128x32 tile, dbuf ----------
__global__ __launch_bounds__(256, 3) void mgemm3_k(
    const unsigned short* __restrict__ Ahp, const unsigned short* __restrict__ Alp,
    const unsigned short* __restrict__ Bth, const unsigned short* __restrict__ Btl,
    const float* __restrict__ bias,
    float* __restrict__ C, int K, int ldc, int nby)
{
    __shared__ unsigned short smem[2][10240];

    const int t = threadIdx.x;
    const int wave = t >> 6, lane = t & 63;
    const int bx = blockIdx.x / nby, by = blockIdx.x % nby;
    const int bm = by * 128, bn = bx * 32;
    const int mw = (wave >> 1) * 64, nw = (wave & 1) * 16;

    const unsigned short* smat;
    int row0, ninst, lmoff;
    if      (wave == 0) { smat = Ahp; row0 = bm; ninst = 8; lmoff = 0; }
    else if (wave == 1) { smat = Alp; row0 = bm; ninst = 8; lmoff = 8192; }
    else if (wave == 2) { smat = Bth; row0 = bn; ninst = 2; lmoff = 16384; }
    else                { smat = Btl; row0 = bn; ninst = 2; lmoff = 18432; }
    const int lr = lane >> 2;
    const int kq = (lane & 3) ^ ((lane >> 3) & 3);
    const unsigned short* gbase = smat + (size_t)(row0 + lr) * K + kq * 8;

    const int la = lane & 15, g4 = lane >> 4;
    const int fo = (g4 ^ ((la >> 1) & 3)) * 8;
    const int aoff = (mw + la) * 32 + fo;
    const int boff = (nw + la) * 32 + fo;

    f32x4 acc[4];
#pragma unroll
    for (int i = 0; i < 4; ++i) acc[i] = (f32x4){0.f, 0.f, 0.f, 0.f};

    auto stage = [&](int buf, int k0) {
        char* lm = (char*)&smem[buf][0] + lmoff;
        const unsigned short* g = gbase + k0;
        if (ninst == 8) {
#pragma unroll
            for (int j = 0; j < 8; ++j)
                async_g2l16(g + (size_t)j * 16 * K, lm + j * 1024);
        } else {
#pragma unroll
            for (int j = 0; j < 2; ++j)
                async_g2l16(g + (size_t)j * 16 * K, lm + j * 1024);
        }
    };

    stage(0, 0);
    DRAIN_VMEM();
    __syncthreads();

    for (int k0 = 0; k0 < K; k0 += 32) {
        const int cur = (k0 >> 5) & 1;
        if (k0 + 32 < K) stage(cur ^ 1, k0 + 32);

        const unsigned short* base = &smem[cur][0];
        const unsigned short* pAh = base + aoff;
        const unsigned short* pAl = base + 4096 + aoff;
        const unsigned short* pBh = base + 8192 + boff;
        const unsigned short* pBl = base + 9216 + boff;

        bf16x8 fah[4], fal[4], fbh, fbl;
#pragma unroll
        for (int i = 0; i < 4; ++i) {
            fah[i] = *(const bf16x8*)(pAh + i * 512);
            fal[i] = *(const bf16x8*)(pAl + i * 512);
        }
        fbh = *(const bf16x8*)(pBh);
        fbl = *(const bf16x8*)(pBl);
#pragma unroll
        for (int i = 0; i < 4; ++i)
            acc[i] = __builtin_amdgcn_mfma_f32_16x16x32_bf16(fah[i], fbh, acc[i], 0, 0, 0);
#pragma unroll
        for (int i = 0; i < 4; ++i)
            acc[i] = __builtin_amdgcn_mfma_f32_16x16x32_bf16(fah[i], fbl, acc[i], 0, 0, 0);
#pragma unroll
        for (int i = 0; i < 4; ++i)
            acc[i] = __builtin_amdgcn_mfma_f32_16x16x32_bf16(fal[i], fbh, acc[i], 0, 0, 0);
        DRAIN_VMEM();
        __syncthreads();
    }

#pragma unroll
    for (int i = 0; i < 4; ++i) {
        int row = bm + mw + i * 16 + g4 * 4;
        int col = bn + nw + la;
        float bz = bias[col];
#pragma unroll
        for (int r = 0; r < 4; ++r) {
            float v = acc[i][r] + bz;
            if (col >= 64) v = softplus_f(v);
            C[(size_t)(row + r) * ldc + col] = v;
        }
    }
}

// ---------------- out-proj GEMM, 128x32 tile, dbuf, 1-term (v12) ----------
// C = ybh @ woh^T + bias. w_out low word dropped: adds ~2^-9-relative
// error (same class as the existing ybh bf16 rounding). Halves MFMA.
__global__ __launch_bounds__(256, 3) void mgemm_out_k(
    const unsigned short* __restrict__ Ah,
    const unsigned short* __restrict__ Bth,
    const float* __restrict__ bias,
    float* __restrict__ C, int K, int ldc, int nby)
{
    __shared__ unsigned short smem[2][6144];

    const int t = threadIdx.x;
    const int wave = t >> 6, lane = t & 63;
    const int bx = blockIdx.x / nby, by = blockIdx.x % nby;
    const int bm = by * 128, bn = bx * 32;
    const int mw = (wave >> 1) * 64, nw = (wave & 1) * 16;

    // staging: wave0 Ah rows 0-63 (4), wave1 Ah rows 64-127 (4),
    //          wave2 Bh (2), wave3 idle (still computes MFMA)
    const unsigned short* smat;
    int row0, ninst, lmoff;
    if      (wave == 0) { smat = Ah;  row0 = bm;      ninst = 4; lmoff = 0; }
    else if (wave == 1) { smat = Ah;  row0 = bm + 64; ninst = 4; lmoff = 4096; }
    else if (wave == 2) { smat = Bth; row0 = bn;      ninst = 2; lmoff = 8192; }
    else                { smat = Bth; row0 = bn;      ninst = 0; lmoff = 10240; }
    const int lr = lane >> 2;
    const int kq = (lane & 3) ^ ((lane >> 3) & 3);
    const unsigned short* gbase = smat + (size_t)(row0 + lr) * K + kq * 8;

    const int la = lane & 15, g4 = lane >> 4;
    const int fo = (g4 ^ ((la >> 1) & 3)) * 8;
    const int aoff = (mw + la) * 32 + fo;
    const int boff = (nw + la) * 32 + fo;

    f32x4 acc[4];
#pragma unroll
    for (int i = 0; i < 4; ++i) acc[i] = (f32x4){0.f, 0.f, 0.f, 0.f};

    auto stage = [&](int buf, int k0) {
        char* lm = (char*)&smem[buf][0] + lmoff;
        const unsigned short* g = gbase + k0;
        if (ninst == 4) {
#pragma unroll
            for (int j = 0; j < 4; ++j)
                async_g2l16(g + (size_t)j * 16 * K, lm + j * 1024);
        } else if (ninst == 2) {
#pragma unroll
            for (int j = 0; j < 2; ++j)
                async_g2l16(g + (size_t)j * 16 * K, lm + j * 1024);
        }
    };

    stage(0, 0);
    DRAIN_VMEM();
    __syncthreads();

    for (int k0 = 0; k0 < K; k0 += 32) {
        const int cur = (k0 >> 5) & 1;
        if (k0 + 32 < K) stage(cur ^ 1, k0 + 32);

        const unsigned short* base = &smem[cur][0];
        const unsigned short* pAh = base + aoff;
        const unsigned short* pBh = base + 4096 + boff;

        bf16x8 fah[4], fbh;
#pragma unroll
        for (int i = 0; i < 4; ++i)
            fah[i] = *(const bf16x8*)(pAh + i * 512);
        fbh = *(const bf16x8*)(pBh);
#pragma unroll
        for (int i = 0; i < 4; ++i)
            acc[i] = __builtin_amdgcn_mfma_f32_16x16x32_bf16(fah[i], fbh, acc[i], 0, 0, 0);
        DRAIN_VMEM();
        __syncthreads();
    }

#pragma unroll
    for (int i = 0; i < 4; ++i) {
        int row = bm + mw + i * 16 + g4 * 4;
        int col = bn + nw + la;
        float bz = bias[col];
#pragma unroll
        for (int r = 0; r < 4; ++r)
            C[(size_t)(row + r) * ldc + col] = acc[i][r] + bz;
    }
}

// ---------------- sequential fractal scan (v8-verbatim) -----------
#define L_LEN 1024
#define CH 32
#define NCH (L_LEN / CH)
#define CHP (CH + 4)

__global__ __launch_bounds__(512) void scan_k(
    const float* __restrict__ xz,    // M x 1536 (silu applied to both halves)
    const float* __restrict__ bcdt,  // M x 896 (BC | dt)
    const float* __restrict__ A_log,
    unsigned short* __restrict__ ybh)  // M x 768 bf16 of y*silu(z)
{
    __shared__ float xdt_t[2][16][CHP];
    __shared__ float ds_t[2][16][CHP];
    __shared__ float B0s[2][16][CHP];
    __shared__ float B1s[2][16][CHP];
    __shared__ float C0s[2][16][CHP];
    __shared__ float C1s[2][16][CHP];
    __shared__ float ysp[2][CH][16][8];

    const int t  = threadIdx.x;
    const int b  = blockIdx.y;
    const int d0 = blockIdx.x * 16;
    const size_t rowbase = (size_t)b * L_LEN;
    const bool is_chain = (t < 256);

    const int n  = t & 15;
    const int dl = (t >> 4) & 15;
    const int np = n >> 1;
    float negAl2e = 0.0f, h0 = 0.0f, h1 = 0.0f;
    float s2 = 1.0f, lT = 0.0f;
    if (is_chain) {
        negAl2e = -__expf(A_log[n]) * LOG2E;
        float phase = 6.283185307179586f * (float)n / 16.0f;
        h0 = 0.01f * cosf(phase);
        h1 = 0.01f * sinf(phase);
        lT = LOG2F(fmaf(h0, h0, fmaf(h1, h1, 1e-8f)));   // s2=1 -> lT = lq0
    }

    const int t2 = t - 256;
    const int hl = t2 >> 2;
    const int hf = (t2 & 3) * 4;

    auto stage = [&](int cc) {
        const int bi = cc & 1;
        if (t2 < 128) {
            size_t row = rowbase + cc * CH + hl;
            float4 rx = *(const float4*)&xz[row * 1536 + d0 + hf];
            float4 rd = *(const float4*)&bcdt[row * 896 + 64 + d0 + hf];
            xdt_t[bi][hf + 0][hl] = rx.x * rd.x;
            xdt_t[bi][hf + 1][hl] = rx.y * rd.y;
            xdt_t[bi][hf + 2][hl] = rx.z * rd.z;
            xdt_t[bi][hf + 3][hl] = rx.w * rd.w;
            ds_t[bi][hf + 0][hl] = rd.x;
            ds_t[bi][hf + 1][hl] = rd.y;
            ds_t[bi][hf + 2][hl] = rd.z;
            ds_t[bi][hf + 3][hl] = rd.w;
        }
#pragma unroll
        for (int i = 0; i < 2; ++i) {
            int idx = t2 + 256 * i;
            int lb = idx >> 4, j4 = (idx & 15) * 4;
            float4 rbc = *(const float4*)&bcdt[(rowbase + cc * CH + lb) * 896 + j4];
            if (j4 < 32) {
                int nn = j4 >> 1;
                B0s[bi][nn][lb]     = rbc.x;
                B1s[bi][nn][lb]     = rbc.y;
                B0s[bi][nn + 1][lb] = rbc.z;
                B1s[bi][nn + 1][lb] = rbc.w;
            } else {
                int nn = (j4 - 32) >> 1;
                C0s[bi][nn][lb]     = rbc.x;
                C1s[bi][nn][lb]     = rbc.y;
                C0s[bi][nn + 1][lb] = rbc.z;
                C1s[bi][nn + 1][lb] = rbc.w;
            }
        }
    };

    auto store_y = [&](int cs) {
        if (t2 >= 128) return;
        const int bi = cs & 1;
        size_t row = rowbase + cs * CH + hl;
        float4 zq = *(const float4*)&xz[row * 1536 + 768 + d0 + hf];
        float yr[4];
#pragma unroll
        for (int j = 0; j < 4; ++j) {
            float4 p0 = *(const float4*)&ysp[bi][hl][hf + j][0];
            float4 p1 = *(const float4*)&ysp[bi][hl][hf + j][4];
            yr[j] = ((p0.x + p0.y) + (p0.z + p0.w)) + ((p1.x + p1.y) + (p1.z + p1.w));
        }
        ushort4 hh;
        hh.x = bf16_rne(yr[0] * zq.x);
        hh.y = bf16_rne(yr[1] * zq.y);
        hh.z = bf16_rne(yr[2] * zq.z);
        hh.w = bf16_rne(yr[3] * zq.w);
        *(ushort4*)&ybh[row * 768 + d0 + hf] = hh;
    };

    if (!is_chain) stage(0);
    __syncthreads();

    for (int c = 0; c < NCH; ++c) {
        if (is_chain) {
            __builtin_amdgcn_s_setprio(1);
            const int bi = c & 1;
            const float* xr  = &xdt_t[bi][dl][0];
            const float* dr  = &ds_t[bi][dl][0];
            const float* b0r = &B0s[bi][n][0];
            const float* b1r = &B1s[bi][n][0];
            const float* c0r = &C0s[bi][n][0];
            const float* c1r = &C1s[bi][n][0];

            float4 px  = *(const float4*)(xr);
            float4 pd  = *(const float4*)(dr);
            float4 pb0 = *(const float4*)(b0r);
            float4 pb1 = *(const float4*)(b1r);
            float4 pc0 = *(const float4*)(c0r);
            float4 pc1 = *(const float4*)(c1r);

            for (int l4 = 0; l4 < CH; l4 += 4) {
                float4 cx = px, cd = pd, cb0 = pb0, cb1 = pb1, cc0 = pc0, cc1 = pc1;
                if (l4 + 4 < CH) {
                    px  = *(const float4*)(xr  + l4 + 4);
                    pd  = *(const float4*)(dr  + l4 + 4);
                    pb0 = *(const float4*)(b0r + l4 + 4);
                    pb1 = *(const float4*)(b1r + l4 + 4);
                    pc0 = *(const float4*)(c0r + l4 + 4);
                    pc1 = *(const float4*)(c1r + l4 + 4);
                }
                const float xv[4]  = {cx.x,  cx.y,  cx.z,  cx.w};
                const float dv[4]  = {cd.x,  cd.y,  cd.z,  cd.w};
                const float C0v[4] = {cc0.x, cc0.y, cc0.z, cc0.w};
                const float C1v[4] = {cc1.x, cc1.y, cc1.z, cc1.w};

                // off-path hoists: coefficient and B*x*dt for the 4 steps
                float cfv[4], bx0[4], bx1[4];
                const float B0v[4] = {cb0.x, cb0.y, cb0.z, cb0.w};
                const float B1v[4] = {cb1.x, cb1.y, cb1.z, cb1.w};
#pragma unroll
                for (int u = 0; u < 4; ++u) {
                    cfv[u] = fmaf(EXP2F(dv[u] * negAl2e), -0.25f, 0.25f);
                    bx0[u] = B0v[u] * xv[u];
                    bx1[u] = B1v[u] * xv[u];
                }

#pragma unroll
                for (int u = 0; u < 4; ++u) {
                    float g = s2 * EXP2F(cfv[u] * lT);
                    h0 = fmaf(h0, g, bx0[u]);
                    h1 = fmaf(h1, g, bx1[u]);
                    float q  = fmaf(h0, h0, fmaf(h1, h1, 1e-8f));
                    float q2 = q * q;                       // Estrin [3/3] Pade
                    float num = fmaf(q2, q + 378.0f,              fmaf(17325.0f, q, 135135.0f));
                    float den = fmaf(q2, fmaf(28.0f, q, 3150.0f), fmaf(62370.0f, q, 135135.0f));
                    s2 = num * RCPF(den);
                    lT = LOG2F(s2 * s2 * q);                // log2(tanh^2 m)

                    float yv = s2 * fmaf(C0v[u], h0, C1v[u] * h1);
                    yv = dpp_add<0xB1>(yv);                 // pair sum
                    if ((n & 1) == 0) ysp[bi][l4 + u][dl][np] = yv;
                }
            }
            __builtin_amdgcn_s_setprio(0);
        } else {
            if (c + 1 < NCH) stage(c + 1);
            if (c >= 1) store_y(c - 1);
        }
        __syncthreads();
    }
    if (!is_chain) store_y(NCH - 1);
}

// ---------------- launcher ----------------
extern "C" void kernel_launch(void* const* d_in, const int* in_sizes, int n_in,
                              void* d_out, int out_size, void* d_ws, size_t ws_size,
                              hipStream_t stream)
{
    const float* x     = (const float*)d_in[0];
    const float* w_in  = (const float*)d_in[1];
    const float* w_xp  = (const float*)d_in[2];
    const float* w_dt  = (const float*)d_in[3];
    const float* b_dt  = (const float*)d_in[4];
    const float* w_out = (const float*)d_in[5];
    const float* b_out = (const float*)d_in[6];
    const float* A_log = (const float*)d_in[7];
    float* out = (float*)d_out;

    const int M = 4096;
    float* xz        = (float*)d_ws;                       // M*1536 f32
    float* bcdt      = xz + (size_t)M * 1536;              // M*896  f32
    float* bias_full = bcdt + (size_t)M * 896;             // 896    f32
    unsigned short* ah   = (unsigned short*)(bias_full + 896);  // M*768
    unsigned short* ybh  = ah   + (size_t)M * 768;         // M*768
    unsigned short* xinh = ybh  + (size_t)M * 768;         // M*768
    unsigned short* xinl = xinh + (size_t)M * 768;         // M*768
    unsigned short* wh   = xinl + (size_t)M * 768;         // 1536*768
    unsigned short* wl   = wh   + (size_t)1536 * 768;
    unsigned short* voh  = wl   + (size_t)1536 * 768;      // 768*768
    unsigned short* vol  = voh  + (size_t)768 * 768;
    unsigned short* wbh  = vol  + (size_t)768 * 768;       // 896*768
    unsigned short* wbl  = wbh  + (size_t)896 * 768;

    dim3 blk(256);

    // 1) conv front: x bf16 + w_in transpose (only what gemm2 needs)
    conv_front_k<<<dim3(1920), blk, 0, stream>>>(x, ah, w_in, wh, wl);

    // 2) gemm2 (768 blocks, z-half 1-term) + conv tail (769 blocks)
    gemm2t_k<<<dim3(1537), blk, 0, stream>>>(
        ah, wh, wl, xz, xinh, xinl,
        w_out, voh, vol, w_xp, w_dt, b_dt, wbh, wbl, bias_full);

    // 3) bcdt = [x_in @ w_xp[:,48:] | softplus(x_in @ W_dt_eff + b_dt)]
    mgemm3_k<<<dim3(28 * 32), blk, 0, stream>>>(
        xinh, xinl, wbh, wbl, bias_full, bcdt, 768, 896, 32);

    // 4) scan -> ybh = bf16(y_scan * silu(z))
    scan_k<<<dim3(48, 4), dim3(512), 0, stream>>>(xz, bcdt, A_log, ybh);

    // 5) out = ybh @ woh^T + b_out   (1-term)
    mgemm_out_k<<<dim3(24 * 32), blk, 0, stream>>>(
        ybh, voh, b_out, out, 768, 768, 32);
}